// Round 2
// baseline (3324.294 us; speedup 1.0000x reference)
//
#include <hip/hip_runtime.h>
#include <hip/hip_bf16.h>

#define BSZ 16
#define Nn 96
#define HD 128
#define NDIM 3
#define HFEAT 6
#define FINC 7
#define BN (BSZ*Nn)

typedef const float* fp;

__device__ __forceinline__ float silu(float x){ return x / (1.f + __expf(-x)); }

// ---------------- embedding: h = [feat, t] @ W_emb + b_emb ; x0 = masked coords
__global__ void k_embed(fp xh, fp t, fp nm, fp W_emb, fp b_emb,
                        float* h, float* x0, float* xA){
  int bn = blockIdx.x, tid = threadIdx.x;
  float nmv = nm[bn];
  if (tid < NDIM){
    float v = xh[bn*(NDIM+HFEAT)+tid] * nmv;
    x0[bn*3+tid] = v; xA[bn*3+tid] = v;
  }
  float acc = b_emb[tid];
  #pragma unroll
  for (int f=0; f<HFEAT; ++f)
    acc += xh[bn*(NDIM+HFEAT)+NDIM+f] * nmv * W_emb[f*HD+tid];
  acc += t[0] * W_emb[HFEAT*HD+tid];   // h_time is NOT node-masked
  h[bn*HD+tid] = acc;
}

// ---------------- Hi = h@W1[:HD] + b1 ; Hj = h@W1[HD:2HD]
__global__ void k_hij(const float* h, fp W1, fp b1, float* Hi, float* Hj){
  __shared__ float sh[HD];
  int bn=blockIdx.x, tid=threadIdx.x;
  sh[tid]=h[bn*HD+tid]; __syncthreads();
  float aI = b1[tid], aJ = 0.f;
  #pragma unroll 8
  for(int k=0;k<HD;++k){ float hv=sh[k]; aI += hv*W1[k*HD+tid]; aJ += hv*W1[(HD+k)*HD+tid]; }
  Hi[bn*HD+tid]=aI; Hj[bn*HD+tid]=aJ;
}

// ---------------- fused pair MLP + aggregate over j  -> agg[b,i,:]
__global__ __launch_bounds__(128) void k_pair(const float* Hi, const float* Hj,
    const float* x, const float* x0, fp nm, fp W1, fp W2, fp b2, float* agg){
  __shared__ __align__(16) float m1buf[2][HD];
  __shared__ float xs[Nn][3], x0s[Nn][3], nms[Nn];
  int bn=blockIdx.x, tid=threadIdx.x;
  int b=bn/Nn, i=bn%Nn;
  for(int idx=tid; idx<Nn*3; idx+=128){ int n=idx/3,d=idx%3;
    xs[n][d]=x[(b*Nn+n)*3+d]; x0s[n][d]=x0[(b*Nn+n)*3+d]; }
  if(tid<Nn) nms[tid]=nm[b*Nn+tid];
  float w2[HD];                     // W2 column resident in VGPRs
  #pragma unroll
  for(int k=0;k<HD;++k) w2[k]=W2[k*HD+tid];
  float wr=W1[(2*HD)*HD+tid], wd=W1[(2*HD+1)*HD+tid];
  float b2v=b2[tid];
  float hiv=Hi[bn*HD+tid];
  __syncthreads();
  float xi0=xs[i][0], xi1=xs[i][1], xi2=xs[i][2];
  float y0=x0s[i][0], y1=x0s[i][1], y2=x0s[i][2];
  float emi=nms[i];
  float accA=0.f;
  for(int j=0;j<Nn;++j){
    float hjv=Hj[(b*Nn+j)*HD+tid];
    float dx0=xi0-xs[j][0], dx1=xi1-xs[j][1], dx2=xi2-xs[j][2];
    float r=dx0*dx0+dx1*dx1+dx2*dx2;
    float e0=y0-x0s[j][0], e1=y1-x0s[j][1], e2=y2-x0s[j][2];
    float d0=e0*e0+e1*e1+e2*e2;
    m1buf[j&1][tid]=silu(hiv+hjv+r*wr+d0*wd);
    __syncthreads();
    const float4* m4=(const float4*)m1buf[j&1];
    float dot=b2v;
    #pragma unroll
    for(int q=0;q<HD/4;++q){ float4 v=m4[q];
      dot+=v.x*w2[4*q]+v.y*w2[4*q+1]+v.z*w2[4*q+2]+v.w*w2[4*q+3]; }
    float em=(j==i)?0.f:emi*nms[j];
    accA+=silu(dot)*em;
  }
  agg[bn*HD+tid]=accA*(1.f/100.f);
}

// ---------------- node update: h = (h + silu(h@Wn1a + agg@Wn1b + b1)@Wn2 + b2)*nm
__global__ void k_node(float* h, const float* agg, fp Wn1, fp bn1, fp Wn2, fp bn2, fp nm){
  __shared__ float shh[HD], sha[HD], shu[HD];
  int bn=blockIdx.x, tid=threadIdx.x;
  shh[tid]=h[bn*HD+tid]; sha[tid]=agg[bn*HD+tid]; __syncthreads();
  float acc=bn1[tid];
  #pragma unroll 4
  for(int k=0;k<HD;++k){ acc += shh[k]*Wn1[k*HD+tid] + sha[k]*Wn1[(HD+k)*HD+tid]; }
  shu[tid]=silu(acc); __syncthreads();
  float acc2=bn2[tid];
  #pragma unroll 8
  for(int k=0;k<HD;++k) acc2 += shu[k]*Wn2[k*HD+tid];
  h[bn*HD+tid]=(shh[tid]+acc2)*nm[bn];
}

// ---------------- fused coord pair MLP: x_new = (x + sum_j cd*(phi@W3)*em /100)*nm
__global__ __launch_bounds__(128) void k_coord(const float* Hi, const float* Hj,
    const float* x, const float* x0, fp nm, fp W1, fp W2, fp b2, fp W3, float* xn){
  __shared__ __align__(16) float m1buf[2][HD];
  __shared__ float xs[Nn][3], x0s[Nn][3], nms[Nn];
  __shared__ float wsum[2][2];
  int bn=blockIdx.x, tid=threadIdx.x;
  int b=bn/Nn, i=bn%Nn;
  for(int idx=tid; idx<Nn*3; idx+=128){ int n=idx/3,d=idx%3;
    xs[n][d]=x[(b*Nn+n)*3+d]; x0s[n][d]=x0[(b*Nn+n)*3+d]; }
  if(tid<Nn) nms[tid]=nm[b*Nn+tid];
  float w2[HD];
  #pragma unroll
  for(int k=0;k<HD;++k) w2[k]=W2[k*HD+tid];
  float wr=W1[(2*HD)*HD+tid], wd=W1[(2*HD+1)*HD+tid];
  float b2v=b2[tid];
  float w3v=W3[tid];
  float hiv=Hi[bn*HD+tid];
  __syncthreads();
  float xi0=xs[i][0], xi1=xs[i][1], xi2=xs[i][2];
  float y0=x0s[i][0], y1=x0s[i][1], y2=x0s[i][2];
  float emi=nms[i];
  int lane=tid&63, wv=tid>>6;
  float acc=0.f;
  for(int j=0;j<Nn;++j){
    float hjv=Hj[(b*Nn+j)*HD+tid];
    float dx0=xi0-xs[j][0], dx1=xi1-xs[j][1], dx2=xi2-xs[j][2];
    float r=dx0*dx0+dx1*dx1+dx2*dx2;
    float e0=y0-x0s[j][0], e1=y1-x0s[j][1], e2=y2-x0s[j][2];
    float d0=e0*e0+e1*e1+e2*e2;
    m1buf[j&1][tid]=silu(hiv+hjv+r*wr+d0*wd);
    __syncthreads();
    const float4* m4=(const float4*)m1buf[j&1];
    float dot=b2v;
    #pragma unroll
    for(int q=0;q<HD/4;++q){ float4 v=m4[q];
      dot+=v.x*w2[4*q]+v.y*w2[4*q+1]+v.z*w2[4*q+2]+v.w*w2[4*q+3]; }
    float p=silu(dot)*w3v;
    p += __shfl_xor(p,1);  p += __shfl_xor(p,2);  p += __shfl_xor(p,4);
    p += __shfl_xor(p,8);  p += __shfl_xor(p,16); p += __shfl_xor(p,32);
    if(lane==0) wsum[j&1][wv]=p;
    __syncthreads();
    float s=wsum[j&1][0]+wsum[j&1][1];
    float em=(j==i)?0.f:emi*nms[j];
    float rinv=rsqrtf(r+1e-8f);
    if(tid<3){
      float dxd=(tid==0)?dx0:((tid==1)?dx1:dx2);
      acc += dxd*rinv*s*em;
    }
  }
  if(tid<3) xn[bn*3+tid]=(xs[i][tid]+acc*(1.f/100.f))*emi;
}

// ---------------- per-batch vel stats: sums of vel and n_per
__global__ void k_velstat(const float* xf, const float* x0, fp nm, float* vstat){
  __shared__ float sh[128];
  int b=blockIdx.x, tid=threadIdx.x;
  float nmv = (tid<Nn)? nm[b*Nn+tid] : 0.f;
  float vals[4];
  #pragma unroll
  for(int d=0;d<3;++d)
    vals[d] = (tid<Nn)? (xf[(b*Nn+tid)*3+d]-x0[(b*Nn+tid)*3+d])*nmv : 0.f;
  vals[3]=nmv;
  #pragma unroll
  for(int q=0;q<4;++q){
    sh[tid]=vals[q]; __syncthreads();
    for(int s=64;s>0;s>>=1){ if(tid<s) sh[tid]+=sh[tid+s]; __syncthreads(); }
    if(tid==0) vstat[b*4+q]=sh[0];
    __syncthreads();
  }
}

// ---------------- output: [vel - mean(vel)*nm , (h@W_out+b_out)[:6]*nm]
__global__ void k_out(const float* h, const float* xf, const float* x0, fp nm,
                      const float* vstat, fp W_out, fp b_out, float* out){
  __shared__ float shh[HD];
  int bn=blockIdx.x, tid=threadIdx.x, b=bn/Nn;
  shh[tid]=h[bn*HD+tid]; __syncthreads();
  float nmv=nm[bn];
  if(tid<3){
    float vel=(xf[bn*3+tid]-x0[bn*3+tid])*nmv;
    float mean=vstat[b*4+tid]/vstat[b*4+3];
    out[bn*(NDIM+HFEAT)+tid]=vel-mean*nmv;
  } else if(tid<3+HFEAT){
    int f=tid-3;
    float acc=b_out[f];
    for(int k=0;k<HD;++k) acc+=shh[k]*W_out[k*FINC+f];
    out[bn*(NDIM+HFEAT)+tid]=acc*nmv;
  }
}

extern "C" void kernel_launch(void* const* d_in, const int* in_sizes, int n_in,
                              void* d_out, int out_size, void* d_ws, size_t ws_size,
                              hipStream_t stream) {
  fp xh   =(fp)d_in[0];
  fp t    =(fp)d_in[1];
  fp nm   =(fp)d_in[2];
  // d_in[3] edge_mask: reproduced exactly as nm_i*nm_j*(i!=j), not read
  fp W_emb=(fp)d_in[4],  b_emb=(fp)d_in[5];
  fp gWe1 =(fp)d_in[6],  gbe1 =(fp)d_in[7];
  fp gWe2 =(fp)d_in[8],  gbe2 =(fp)d_in[9];
  fp gWn1 =(fp)d_in[10], gbn1 =(fp)d_in[11];
  fp gWn2 =(fp)d_in[12], gbn2 =(fp)d_in[13];
  fp eWc1 =(fp)d_in[14], ebc1 =(fp)d_in[15];
  fp eWc2 =(fp)d_in[16], ebc2 =(fp)d_in[17];
  fp eWc3 =(fp)d_in[18];
  fp W_out=(fp)d_in[19], b_out=(fp)d_in[20];

  float* ws=(float*)d_ws;
  float* h    = ws;               // BN*HD
  float* Hi   = h   + BN*HD;
  float* Hj   = Hi  + BN*HD;
  float* agg  = Hj  + BN*HD;
  float* x0   = agg + BN*HD;      // BN*3
  float* xA   = x0  + BN*3;
  float* xB   = xA  + BN*3;
  float* vstat= xB  + BN*3;       // BSZ*4

  k_embed<<<BN,128,0,stream>>>(xh,t,nm,W_emb,b_emb,h,x0,xA);
  float* xc=xA; float* xn=xB;
  for(int l=0;l<4;++l){
    for(int s=0;s<2;++s){
      int g=l*2+s;
      k_hij <<<BN,128,0,stream>>>(h, gWe1+(size_t)g*258*HD, gbe1+(size_t)g*HD, Hi, Hj);
      k_pair<<<BN,128,0,stream>>>(Hi,Hj,xc,x0,nm,
            gWe1+(size_t)g*258*HD, gWe2+(size_t)g*HD*HD, gbe2+(size_t)g*HD, agg);
      k_node<<<BN,128,0,stream>>>(h,agg,
            gWn1+(size_t)g*256*HD, gbn1+(size_t)g*HD,
            gWn2+(size_t)g*HD*HD, gbn2+(size_t)g*HD, nm);
    }
    k_hij  <<<BN,128,0,stream>>>(h, eWc1+(size_t)l*258*HD, ebc1+(size_t)l*HD, Hi, Hj);
    k_coord<<<BN,128,0,stream>>>(Hi,Hj,xc,x0,nm,
            eWc1+(size_t)l*258*HD, eWc2+(size_t)l*HD*HD, ebc2+(size_t)l*HD,
            eWc3+(size_t)l*HD, xn);
    float* tmp=xc; xc=xn; xn=tmp;
  }
  k_velstat<<<BSZ,128,0,stream>>>(xc,x0,nm,vstat);
  k_out   <<<BN,128,0,stream>>>(h,xc,x0,nm,vstat,W_out,b_out,(float*)d_out);
}

// Round 3
// 1828.482 us; speedup vs baseline: 1.8181x; 1.8181x over previous
//
#include <hip/hip_runtime.h>
#include <hip/hip_bf16.h>

#define BSZ 16
#define Nn 96
#define HD 128
#define NDIM 3
#define HFEAT 6
#define FINC 7
#define BN (BSZ*Nn)
#define S1 129   // m1 LDS row stride (floats): odd -> conflict-free column access

typedef const float* fp;

__device__ __forceinline__ float silu(float x){ return x / (1.f + __expf(-x)); }

// ---------------- embedding: h = [feat, t] @ W_emb + b_emb ; x0 = masked coords
__global__ void k_embed(fp xh, fp t, fp nm, fp W_emb, fp b_emb,
                        float* h, float* x0, float* xA){
  int bn = blockIdx.x, tid = threadIdx.x;
  float nmv = nm[bn];
  if (tid < NDIM){
    float v = xh[bn*(NDIM+HFEAT)+tid] * nmv;
    x0[bn*3+tid] = v; xA[bn*3+tid] = v;
  }
  float acc = b_emb[tid];
  #pragma unroll
  for (int f=0; f<HFEAT; ++f)
    acc += xh[bn*(NDIM+HFEAT)+NDIM+f] * nmv * W_emb[f*HD+tid];
  acc += t[0] * W_emb[HFEAT*HD+tid];   // h_time is NOT node-masked
  h[bn*HD+tid] = acc;
}

// ---------------- Hi = h@W1[:HD] + b1 ; Hj = h@W1[HD:2HD]   (4 nodes per block)
__global__ __launch_bounds__(512) void k_hij(const float* h, fp W1, fp b1, float* Hi, float* Hj){
  __shared__ float sh[4][HD];
  int t=threadIdx.x, sub=t>>7, tid=t&127;
  int bn=blockIdx.x*4+sub;
  sh[sub][tid]=h[bn*HD+tid]; __syncthreads();
  float aI = b1[tid], aJ = 0.f;
  #pragma unroll 8
  for(int k=0;k<HD;++k){ float hv=sh[sub][k]; aI += hv*W1[k*HD+tid]; aJ += hv*W1[(HD+k)*HD+tid]; }
  Hi[bn*HD+tid]=aI; Hj[bn*HD+tid]=aJ;
}

// ---------------- fused pair MLP + aggregate over j  -> agg[b,i,:]
// One block per (b,i). Phase1: m1[j][k] in LDS. Phase2: tiled GEMM m1 @ W2.
__global__ __launch_bounds__(512) void k_pair(const float* Hi, const float* Hj,
    const float* x, const float* x0, fp nm, fp W1, fp W2, fp b2, float* agg){
  __shared__ float m1[Nn*S1];          // 49.5 KB
  __shared__ float w2s[HD*HD];         // 64 KB
  __shared__ float xs[Nn][3], x0s[Nn][3], nms[Nn], rs[Nn], d0s[Nn];
  __shared__ float redbuf[HD*17];      // 8.7 KB
  int tid=threadIdx.x, bn=blockIdx.x;
  int b=bn/Nn, i=bn%Nn;
  for(int idx=tid; idx<Nn*3; idx+=512){ int n=idx/3,d=idx%3;
    xs[n][d]=x[(b*Nn+n)*3+d]; x0s[n][d]=x0[(b*Nn+n)*3+d]; }
  if(tid<Nn) nms[tid]=nm[b*Nn+tid];
  __syncthreads();
  if(tid<Nn){
    float dx0=xs[i][0]-xs[tid][0], dx1=xs[i][1]-xs[tid][1], dx2=xs[i][2]-xs[tid][2];
    rs[tid]=dx0*dx0+dx1*dx1+dx2*dx2;
    float e0=x0s[i][0]-x0s[tid][0], e1=x0s[i][1]-x0s[tid][1], e2=x0s[i][2]-x0s[tid][2];
    d0s[tid]=e0*e0+e1*e1+e2*e2;
  }
  { const float4* W2v=(const float4*)W2; float4* w2sv=(float4*)w2s;
    for(int idx=tid; idx<HD*HD/4; idx+=512) w2sv[idx]=W2v[idx]; }
  __syncthreads();
  // phase 1: m1[j][k] = silu(Hi + Hj + r*wr + d0*wd)   (Hi carries b1)
  { int k=tid&127, jp=tid>>7;
    float hiv=Hi[bn*HD+k];
    float wrv=W1[(2*HD)*HD+k], wdv=W1[(2*HD+1)*HD+k];
    for(int j=jp;j<Nn;j+=4){
      float hjv=Hj[(b*Nn+j)*HD+k];
      m1[j*S1+k]=silu(hiv+hjv+rs[j]*wrv+d0s[j]*wdv);
    } }
  __syncthreads();
  // phase 2: GEMM  (thread tile 6j x 4c; ct=tid&31 -> c0=ct*4, jt=tid>>5 -> j0=jt*6)
  int ct=tid&31, jt=tid>>5;
  int c0=ct*4, j0=jt*6;
  float acc[6][4]={{0.f}};
  #pragma unroll 2
  for(int k=0;k<HD;++k){
    float4 bv=*((const float4*)&w2s[k*HD+c0]);
    float a[6];
    #pragma unroll
    for(int m=0;m<6;++m) a[m]=m1[(j0+m)*S1+k];
    #pragma unroll
    for(int m=0;m<6;++m){
      acc[m][0]+=a[m]*bv.x; acc[m][1]+=a[m]*bv.y;
      acc[m][2]+=a[m]*bv.z; acc[m][3]+=a[m]*bv.w;
    }
  }
  // epilogue: silu(+b2), mask, reduce over j
  float b2v[4], part[4]={0.f,0.f,0.f,0.f};
  #pragma unroll
  for(int cc=0;cc<4;++cc) b2v[cc]=b2[c0+cc];
  #pragma unroll
  for(int m=0;m<6;++m){
    int j=j0+m;
    float em=(j==i)?0.f:nms[j];
    #pragma unroll
    for(int cc=0;cc<4;++cc) part[cc]+=silu(acc[m][cc]+b2v[cc])*em;
  }
  #pragma unroll
  for(int cc=0;cc<4;++cc) redbuf[(c0+cc)*17+jt]=part[cc];
  __syncthreads();
  if(tid<HD){
    float s=0.f;
    #pragma unroll
    for(int q=0;q<16;++q) s+=redbuf[tid*17+q];
    agg[bn*HD+tid]=s*nms[i]*(1.f/100.f);
  }
}

// ---------------- node update (4 nodes per block)
__global__ __launch_bounds__(512) void k_node(float* h, const float* agg, fp Wn1, fp bn1, fp Wn2, fp bn2, fp nm){
  __shared__ float shh[4][HD], sha[4][HD], shu[4][HD];
  int t=threadIdx.x, sub=t>>7, tid=t&127;
  int bn=blockIdx.x*4+sub;
  shh[sub][tid]=h[bn*HD+tid]; sha[sub][tid]=agg[bn*HD+tid]; __syncthreads();
  float acc=bn1[tid];
  #pragma unroll 4
  for(int k=0;k<HD;++k){ acc += shh[sub][k]*Wn1[k*HD+tid] + sha[sub][k]*Wn1[(HD+k)*HD+tid]; }
  shu[sub][tid]=silu(acc); __syncthreads();
  float acc2=bn2[tid];
  #pragma unroll 8
  for(int k=0;k<HD;++k) acc2 += shu[sub][k]*Wn2[k*HD+tid];
  h[bn*HD+tid]=(shh[sub][tid]+acc2)*nm[bn];
}

// ---------------- fused coord pair MLP
__global__ __launch_bounds__(512) void k_coord(const float* Hi, const float* Hj,
    const float* x, const float* x0, fp nm, fp W1, fp W2, fp b2, fp W3, float* xn){
  __shared__ float m1[Nn*S1];
  __shared__ float w2s[HD*HD];
  __shared__ float xs[Nn][3], x0s[Nn][3], nms[Nn], rs[Nn], d0s[Nn];
  __shared__ float redJ[Nn*33];        // per-j partials over ct
  __shared__ float sjs[Nn];
  int tid=threadIdx.x, bn=blockIdx.x;
  int b=bn/Nn, i=bn%Nn;
  for(int idx=tid; idx<Nn*3; idx+=512){ int n=idx/3,d=idx%3;
    xs[n][d]=x[(b*Nn+n)*3+d]; x0s[n][d]=x0[(b*Nn+n)*3+d]; }
  if(tid<Nn) nms[tid]=nm[b*Nn+tid];
  __syncthreads();
  if(tid<Nn){
    float dx0=xs[i][0]-xs[tid][0], dx1=xs[i][1]-xs[tid][1], dx2=xs[i][2]-xs[tid][2];
    rs[tid]=dx0*dx0+dx1*dx1+dx2*dx2;
    float e0=x0s[i][0]-x0s[tid][0], e1=x0s[i][1]-x0s[tid][1], e2=x0s[i][2]-x0s[tid][2];
    d0s[tid]=e0*e0+e1*e1+e2*e2;
  }
  { const float4* W2v=(const float4*)W2; float4* w2sv=(float4*)w2s;
    for(int idx=tid; idx<HD*HD/4; idx+=512) w2sv[idx]=W2v[idx]; }
  __syncthreads();
  { int k=tid&127, jp=tid>>7;
    float hiv=Hi[bn*HD+k];
    float wrv=W1[(2*HD)*HD+k], wdv=W1[(2*HD+1)*HD+k];
    for(int j=jp;j<Nn;j+=4){
      float hjv=Hj[(b*Nn+j)*HD+k];
      m1[j*S1+k]=silu(hiv+hjv+rs[j]*wrv+d0s[j]*wdv);
    } }
  __syncthreads();
  int ct=tid&31, jt=tid>>5;
  int c0=ct*4, j0=jt*6;
  float acc[6][4]={{0.f}};
  #pragma unroll 2
  for(int k=0;k<HD;++k){
    float4 bv=*((const float4*)&w2s[k*HD+c0]);
    float a[6];
    #pragma unroll
    for(int m=0;m<6;++m) a[m]=m1[(j0+m)*S1+k];
    #pragma unroll
    for(int m=0;m<6;++m){
      acc[m][0]+=a[m]*bv.x; acc[m][1]+=a[m]*bv.y;
      acc[m][2]+=a[m]*bv.z; acc[m][3]+=a[m]*bv.w;
    }
  }
  float b2v[4], w3v[4];
  #pragma unroll
  for(int cc=0;cc<4;++cc){ b2v[cc]=b2[c0+cc]; w3v[cc]=W3[c0+cc]; }
  #pragma unroll
  for(int m=0;m<6;++m){
    float pj=0.f;
    #pragma unroll
    for(int cc=0;cc<4;++cc) pj+=silu(acc[m][cc]+b2v[cc])*w3v[cc];
    redJ[(j0+m)*33+ct]=pj;
  }
  __syncthreads();
  if(tid<Nn){
    float s=0.f;
    #pragma unroll
    for(int q=0;q<32;++q) s+=redJ[tid*33+q];
    float em=(tid==i)?0.f:nms[tid];
    sjs[tid]=s*em*rsqrtf(rs[tid]+1e-8f);
  }
  __syncthreads();
  if(tid<3){
    float sum=0.f;
    for(int j=0;j<Nn;++j) sum+=(xs[i][tid]-xs[j][tid])*sjs[j];
    xn[bn*3+tid]=(xs[i][tid]+sum*(1.f/100.f))*nms[i];
  }
}

// ---------------- per-batch vel stats: sums of vel and n_per
__global__ void k_velstat(const float* xf, const float* x0, fp nm, float* vstat){
  __shared__ float sh[128];
  int b=blockIdx.x, tid=threadIdx.x;
  float nmv = (tid<Nn)? nm[b*Nn+tid] : 0.f;
  float vals[4];
  #pragma unroll
  for(int d=0;d<3;++d)
    vals[d] = (tid<Nn)? (xf[(b*Nn+tid)*3+d]-x0[(b*Nn+tid)*3+d])*nmv : 0.f;
  vals[3]=nmv;
  #pragma unroll
  for(int q=0;q<4;++q){
    sh[tid]=vals[q]; __syncthreads();
    for(int s=64;s>0;s>>=1){ if(tid<s) sh[tid]+=sh[tid+s]; __syncthreads(); }
    if(tid==0) vstat[b*4+q]=sh[0];
    __syncthreads();
  }
}

// ---------------- output: [vel - mean(vel)*nm , (h@W_out+b_out)[:6]*nm]
__global__ void k_out(const float* h, const float* xf, const float* x0, fp nm,
                      const float* vstat, fp W_out, fp b_out, float* out){
  __shared__ float shh[HD];
  int bn=blockIdx.x, tid=threadIdx.x, b=bn/Nn;
  shh[tid]=h[bn*HD+tid]; __syncthreads();
  float nmv=nm[bn];
  if(tid<3){
    float vel=(xf[bn*3+tid]-x0[bn*3+tid])*nmv;
    float mean=vstat[b*4+tid]/vstat[b*4+3];
    out[bn*(NDIM+HFEAT)+tid]=vel-mean*nmv;
  } else if(tid<3+HFEAT){
    int f=tid-3;
    float acc=b_out[f];
    for(int k=0;k<HD;++k) acc+=shh[k]*W_out[k*FINC+f];
    out[bn*(NDIM+HFEAT)+tid]=acc*nmv;
  }
}

extern "C" void kernel_launch(void* const* d_in, const int* in_sizes, int n_in,
                              void* d_out, int out_size, void* d_ws, size_t ws_size,
                              hipStream_t stream) {
  fp xh   =(fp)d_in[0];
  fp t    =(fp)d_in[1];
  fp nm   =(fp)d_in[2];
  // d_in[3] edge_mask: reproduced exactly as nm_i*nm_j*(i!=j), not read
  fp W_emb=(fp)d_in[4],  b_emb=(fp)d_in[5];
  fp gWe1 =(fp)d_in[6],  gbe1 =(fp)d_in[7];
  fp gWe2 =(fp)d_in[8],  gbe2 =(fp)d_in[9];
  fp gWn1 =(fp)d_in[10], gbn1 =(fp)d_in[11];
  fp gWn2 =(fp)d_in[12], gbn2 =(fp)d_in[13];
  fp eWc1 =(fp)d_in[14], ebc1 =(fp)d_in[15];
  fp eWc2 =(fp)d_in[16], ebc2 =(fp)d_in[17];
  fp eWc3 =(fp)d_in[18];
  fp W_out=(fp)d_in[19], b_out=(fp)d_in[20];

  float* ws=(float*)d_ws;
  float* h    = ws;               // BN*HD
  float* Hi   = h   + BN*HD;
  float* Hj   = Hi  + BN*HD;
  float* agg  = Hj  + BN*HD;
  float* x0   = agg + BN*HD;      // BN*3
  float* xA   = x0  + BN*3;
  float* xB   = xA  + BN*3;
  float* vstat= xB  + BN*3;       // BSZ*4

  k_embed<<<BN,128,0,stream>>>(xh,t,nm,W_emb,b_emb,h,x0,xA);
  float* xc=xA; float* xn=xB;
  for(int l=0;l<4;++l){
    for(int s=0;s<2;++s){
      int g=l*2+s;
      k_hij <<<BN/4,512,0,stream>>>(h, gWe1+(size_t)g*258*HD, gbe1+(size_t)g*HD, Hi, Hj);
      k_pair<<<BN,512,0,stream>>>(Hi,Hj,xc,x0,nm,
            gWe1+(size_t)g*258*HD, gWe2+(size_t)g*HD*HD, gbe2+(size_t)g*HD, agg);
      k_node<<<BN/4,512,0,stream>>>(h,agg,
            gWn1+(size_t)g*256*HD, gbn1+(size_t)g*HD,
            gWn2+(size_t)g*HD*HD, gbn2+(size_t)g*HD, nm);
    }
    k_hij  <<<BN/4,512,0,stream>>>(h, eWc1+(size_t)l*258*HD, ebc1+(size_t)l*HD, Hi, Hj);
    k_coord<<<BN,512,0,stream>>>(Hi,Hj,xc,x0,nm,
            eWc1+(size_t)l*258*HD, eWc2+(size_t)l*HD*HD, ebc2+(size_t)l*HD,
            eWc3+(size_t)l*HD, xn);
    float* tmp=xc; xc=xn; xn=tmp;
  }
  k_velstat<<<BSZ,128,0,stream>>>(xc,x0,nm,vstat);
  k_out   <<<BN,128,0,stream>>>(h,xc,x0,nm,vstat,W_out,b_out,(float*)d_out);
}

// Round 4
// 743.110 us; speedup vs baseline: 4.4735x; 2.4606x over previous
//
#include <hip/hip_runtime.h>
#include <hip/hip_bf16.h>

#define BSZ 16
#define Nn 96
#define HD 128
#define NDIM 3
#define HFEAT 6
#define FINC 7
#define BN (BSZ*Nn)

typedef const float* fp;
typedef __bf16 bf16x8_t __attribute__((ext_vector_type(8)));
typedef float  f32x4_t  __attribute__((ext_vector_type(4)));

__device__ __forceinline__ float silu(float x){ return x / (1.f + __expf(-x)); }
__device__ __forceinline__ unsigned short f2b(float x){
  unsigned u = __float_as_uint(x);
  unsigned r = u + 0x7FFF + ((u>>16)&1);       // RNE
  return (unsigned short)(r>>16);
}

// ---------------- one-time: W2 (12 matrices) -> bf16 B-fragment layout
// B-frag: element idx = ((nt*4+kt)*64 + lane)*8 + jj ; value = W2[k][n],
//   k = kt*32 + (lane>>4)*8 + jj, n = nt*16 + (lane&15)
__global__ void k_prep(fp gWe2, fp eWc2, unsigned short* w2b){
  int mid = blockIdx.x;
  const float* src = (mid<8)? gWe2 + (size_t)mid*HD*HD : eWc2 + (size_t)(mid-8)*HD*HD;
  unsigned short* dst = w2b + (size_t)mid*HD*HD;
  for (int idx = threadIdx.x; idx < HD*HD; idx += 256){
    int jj = idx&7, l=(idx>>3)&63, kt=(idx>>9)&3, nt=idx>>11;
    int k = kt*32 + (l>>4)*8 + jj, n = nt*16 + (l&15);
    dst[idx] = f2b(src[k*HD+n]);
  }
}

// ---------------- embedding
__global__ void k_embed(fp xh, fp t, fp nm, fp W_emb, fp b_emb,
                        float* h, float* x0, float* xA){
  int bn = blockIdx.x, tid = threadIdx.x;
  float nmv = nm[bn];
  if (tid < NDIM){
    float v = xh[bn*(NDIM+HFEAT)+tid] * nmv;
    x0[bn*3+tid] = v; xA[bn*3+tid] = v;
  }
  float acc = b_emb[tid];
  #pragma unroll
  for (int f=0; f<HFEAT; ++f)
    acc += xh[bn*(NDIM+HFEAT)+NDIM+f] * nmv * W_emb[f*HD+tid];
  acc += t[0] * W_emb[HFEAT*HD+tid];
  h[bn*HD+tid] = acc;
}

// ---------------- Hi = h@W1[:HD] + b1 ; Hj = h@W1[HD:2HD]   (4 nodes/block)
__global__ __launch_bounds__(512) void k_hij(const float* h, fp W1, fp b1, float* Hi, float* Hj){
  __shared__ float sh[4][HD];
  int t=threadIdx.x, sub=t>>7, tid=t&127;
  int bn=blockIdx.x*4+sub;
  sh[sub][tid]=h[bn*HD+tid]; __syncthreads();
  float aI = b1[tid], aJ = 0.f;
  #pragma unroll 8
  for(int k=0;k<HD;++k){ float hv=sh[sub][k]; aI += hv*W1[k*HD+tid]; aJ += hv*W1[(HD+k)*HD+tid]; }
  Hi[bn*HD+tid]=aI; Hj[bn*HD+tid]=aJ;
}

// ============ fused pair MLP (MFMA) + aggregate over j -> agg[b,i,:] ============
// Block = one (b,i). m1[96][128] built in LDS in bf16 A-frag order; GEMM vs W2
// B-frags (global bf16); epilogue silu+mask+reduce over j.
__global__ __launch_bounds__(512) void k_pair(const float* Hi, const float* Hj,
    const float* x, const float* x0, fp nm, fp W1,
    const unsigned short* w2m, fp b2, float* agg){
  __shared__ unsigned int m1f[6144];                 // 24 KB bf16-pair A-frags
  __shared__ float xs[Nn][3], x0s[Nn][3], nms[Nn], rs[Nn], d0s[Nn];
  __shared__ float red[2][HD];
  int tid=threadIdx.x, bn=blockIdx.x;
  int b=bn/Nn, i=bn%Nn;
  int l=tid&63, w=tid>>6, wm=w>>2, wn=w&3;

  // preload B-frags (pure global; overlaps staging/phase1)
  bf16x8_t Bf[2][4];
  #pragma unroll
  for(int s=0;s<2;++s){ int nt=wn*2+s;
    #pragma unroll
    for(int kt=0;kt<4;++kt)
      Bf[s][kt] = *(const bf16x8_t*)(w2m + (((nt*4+kt)*64 + l)*8));
  }

  for(int idx=tid; idx<Nn*3; idx+=512){ int n=idx/3,d=idx%3;
    xs[n][d]=x[(b*Nn+n)*3+d]; x0s[n][d]=x0[(b*Nn+n)*3+d]; }
  if(tid<Nn) nms[tid]=nm[b*Nn+tid];
  __syncthreads();
  if(tid<Nn){
    float dx0=xs[i][0]-xs[tid][0], dx1=xs[i][1]-xs[tid][1], dx2=xs[i][2]-xs[tid][2];
    rs[tid]=dx0*dx0+dx1*dx1+dx2*dx2;
    float e0=x0s[i][0]-x0s[tid][0], e1=x0s[i][1]-x0s[tid][1], e2=x0s[i][2]-x0s[tid][2];
    d0s[tid]=e0*e0+e1*e1+e2*e2;
  }
  __syncthreads();

  // phase 1: m1[j][k],k pair (2k) per thread, 12 j's; write packed bf16x2
  { int kp=tid&63, jg=tid>>6;
    float2 hi = ((const float2*)&Hi[(size_t)bn*HD])[kp];
    float2 wr = ((const float2*)&W1[(size_t)(2*HD)*HD])[kp];
    float2 wd = ((const float2*)&W1[(size_t)(2*HD+1)*HD])[kp];
    int kt = kp>>4, lanep = 16*((kp>>2)&3), dsub = kp&3;
    #pragma unroll 4
    for(int it=0; it<12; ++it){
      int j = jg*12 + it;
      float2 hj = ((const float2*)&Hj[(size_t)(b*Nn+j)*HD])[kp];
      float m0 = silu(hi.x + hj.x + rs[j]*wr.x + d0s[j]*wd.x);
      float m1v= silu(hi.y + hj.y + rs[j]*wr.y + d0s[j]*wd.y);
      int mt=j>>4, lane=(j&15)+lanep;
      m1f[((mt*4+kt)*64 + lane)*4 + dsub] = (unsigned)f2b(m0) | ((unsigned)f2b(m1v)<<16);
    } }
  __syncthreads();

  // phase 2: MFMA GEMM. wave (wm,wn): mtiles wm*3..+2, ntiles wn*2..+1
  f32x4_t acc[3][2];
  #pragma unroll
  for(int a=0;a<3;++a){ acc[a][0]=(f32x4_t){0.f,0.f,0.f,0.f}; acc[a][1]=(f32x4_t){0.f,0.f,0.f,0.f}; }
  #pragma unroll
  for(int kt=0;kt<4;++kt){
    #pragma unroll
    for(int a=0;a<3;++a){
      int mt=wm*3+a;
      bf16x8_t A = *(const bf16x8_t*)((const unsigned short*)m1f + (((mt*4+kt)*64 + l)*8));
      acc[a][0]=__builtin_amdgcn_mfma_f32_16x16x32_bf16(A, Bf[0][kt], acc[a][0], 0,0,0);
      acc[a][1]=__builtin_amdgcn_mfma_f32_16x16x32_bf16(A, Bf[1][kt], acc[a][1], 0,0,0);
    }
  }

  // epilogue: silu(+b2)*em, reduce over j
  float b2v0=b2[wn*32 + (l&15)], b2v1=b2[wn*32 + 16 + (l&15)];
  float p0=0.f, p1=0.f;
  #pragma unroll
  for(int a=0;a<3;++a){
    #pragma unroll
    for(int r=0;r<4;++r){
      int j=(wm*3+a)*16 + (l>>4)*4 + r;
      float emj=(j==i)?0.f:nms[j];
      p0 += silu(acc[a][0][r]+b2v0)*emj;
      p1 += silu(acc[a][1][r]+b2v1)*emj;
    }
  }
  p0 += __shfl_xor(p0,16); p0 += __shfl_xor(p0,32);
  p1 += __shfl_xor(p1,16); p1 += __shfl_xor(p1,32);
  if(l<16){ red[wm][wn*32+l]=p0; red[wm][wn*32+16+l]=p1; }
  __syncthreads();
  if(tid<HD) agg[(size_t)bn*HD+tid]=(red[0][tid]+red[1][tid])*nms[i]*(1.f/100.f);
}

// ---------------- node update (4 nodes/block)
__global__ __launch_bounds__(512) void k_node(float* h, const float* agg, fp Wn1, fp bn1, fp Wn2, fp bn2, fp nm){
  __shared__ float shh[4][HD], sha[4][HD], shu[4][HD];
  int t=threadIdx.x, sub=t>>7, tid=t&127;
  int bn=blockIdx.x*4+sub;
  shh[sub][tid]=h[bn*HD+tid]; sha[sub][tid]=agg[bn*HD+tid]; __syncthreads();
  float acc=bn1[tid];
  #pragma unroll 4
  for(int k=0;k<HD;++k){ acc += shh[sub][k]*Wn1[k*HD+tid] + sha[sub][k]*Wn1[(HD+k)*HD+tid]; }
  shu[sub][tid]=silu(acc); __syncthreads();
  float acc2=bn2[tid];
  #pragma unroll 8
  for(int k=0;k<HD;++k) acc2 += shu[sub][k]*Wn2[k*HD+tid];
  h[bn*HD+tid]=(shh[sub][tid]+acc2)*nm[bn];
}

// ============ fused coord pair MLP (MFMA) ============
__global__ __launch_bounds__(512) void k_coord(const float* Hi, const float* Hj,
    const float* x, const float* x0, fp nm, fp W1,
    const unsigned short* w2m, fp b2, fp W3, float* xn){
  __shared__ unsigned int m1f[6144];
  __shared__ float xs[Nn][3], x0s[Nn][3], nms[Nn], rs[Nn], d0s[Nn];
  __shared__ float redJ[4][Nn];
  __shared__ float sjs[Nn];
  int tid=threadIdx.x, bn=blockIdx.x;
  int b=bn/Nn, i=bn%Nn;
  int l=tid&63, w=tid>>6, wm=w>>2, wn=w&3;

  bf16x8_t Bf[2][4];
  #pragma unroll
  for(int s=0;s<2;++s){ int nt=wn*2+s;
    #pragma unroll
    for(int kt=0;kt<4;++kt)
      Bf[s][kt] = *(const bf16x8_t*)(w2m + (((nt*4+kt)*64 + l)*8));
  }

  for(int idx=tid; idx<Nn*3; idx+=512){ int n=idx/3,d=idx%3;
    xs[n][d]=x[(b*Nn+n)*3+d]; x0s[n][d]=x0[(b*Nn+n)*3+d]; }
  if(tid<Nn) nms[tid]=nm[b*Nn+tid];
  __syncthreads();
  if(tid<Nn){
    float dx0=xs[i][0]-xs[tid][0], dx1=xs[i][1]-xs[tid][1], dx2=xs[i][2]-xs[tid][2];
    rs[tid]=dx0*dx0+dx1*dx1+dx2*dx2;
    float e0=x0s[i][0]-x0s[tid][0], e1=x0s[i][1]-x0s[tid][1], e2=x0s[i][2]-x0s[tid][2];
    d0s[tid]=e0*e0+e1*e1+e2*e2;
  }
  __syncthreads();

  { int kp=tid&63, jg=tid>>6;
    float2 hi = ((const float2*)&Hi[(size_t)bn*HD])[kp];
    float2 wr = ((const float2*)&W1[(size_t)(2*HD)*HD])[kp];
    float2 wd = ((const float2*)&W1[(size_t)(2*HD+1)*HD])[kp];
    int kt = kp>>4, lanep = 16*((kp>>2)&3), dsub = kp&3;
    #pragma unroll 4
    for(int it=0; it<12; ++it){
      int j = jg*12 + it;
      float2 hj = ((const float2*)&Hj[(size_t)(b*Nn+j)*HD])[kp];
      float m0 = silu(hi.x + hj.x + rs[j]*wr.x + d0s[j]*wd.x);
      float m1v= silu(hi.y + hj.y + rs[j]*wr.y + d0s[j]*wd.y);
      int mt=j>>4, lane=(j&15)+lanep;
      m1f[((mt*4+kt)*64 + lane)*4 + dsub] = (unsigned)f2b(m0) | ((unsigned)f2b(m1v)<<16);
    } }
  __syncthreads();

  f32x4_t acc[3][2];
  #pragma unroll
  for(int a=0;a<3;++a){ acc[a][0]=(f32x4_t){0.f,0.f,0.f,0.f}; acc[a][1]=(f32x4_t){0.f,0.f,0.f,0.f}; }
  #pragma unroll
  for(int kt=0;kt<4;++kt){
    #pragma unroll
    for(int a=0;a<3;++a){
      int mt=wm*3+a;
      bf16x8_t A = *(const bf16x8_t*)((const unsigned short*)m1f + (((mt*4+kt)*64 + l)*8));
      acc[a][0]=__builtin_amdgcn_mfma_f32_16x16x32_bf16(A, Bf[0][kt], acc[a][0], 0,0,0);
      acc[a][1]=__builtin_amdgcn_mfma_f32_16x16x32_bf16(A, Bf[1][kt], acc[a][1], 0,0,0);
    }
  }

  // epilogue: pj = sum_c silu(+b2)*w3 ; reduce over the 16 lane-columns
  float b2v0=b2[wn*32 + (l&15)], b2v1=b2[wn*32 + 16 + (l&15)];
  float w3v0=W3[wn*32 + (l&15)], w3v1=W3[wn*32 + 16 + (l&15)];
  float q[3][4];
  #pragma unroll
  for(int a=0;a<3;++a)
    #pragma unroll
    for(int r=0;r<4;++r)
      q[a][r]=silu(acc[a][0][r]+b2v0)*w3v0 + silu(acc[a][1][r]+b2v1)*w3v1;
  #pragma unroll
  for(int d=1;d<16;d<<=1){
    #pragma unroll
    for(int a=0;a<3;++a)
      #pragma unroll
      for(int r=0;r<4;++r)
        q[a][r] += __shfl_xor(q[a][r], d);
  }
  if((l&15)==0){
    int quad=l>>4;
    #pragma unroll
    for(int a=0;a<3;++a)
      #pragma unroll
      for(int r=0;r<4;++r)
        redJ[wn][(wm*3+a)*16 + quad*4 + r]=q[a][r];
  }
  __syncthreads();
  if(tid<Nn){
    float pj=redJ[0][tid]+redJ[1][tid]+redJ[2][tid]+redJ[3][tid];
    float em=(tid==i)?0.f:nms[tid];
    sjs[tid]=pj*em*rsqrtf(rs[tid]+1e-8f);
  }
  __syncthreads();
  if(tid<3){
    float xi=xs[i][tid], sum=0.f;
    for(int j=0;j<Nn;++j) sum+=(xi-xs[j][tid])*sjs[j];
    xn[bn*3+tid]=(xi+sum*(1.f/100.f))*nms[i];
  }
}

// ---------------- per-batch vel stats
__global__ void k_velstat(const float* xf, const float* x0, fp nm, float* vstat){
  __shared__ float sh[128];
  int b=blockIdx.x, tid=threadIdx.x;
  float nmv = (tid<Nn)? nm[b*Nn+tid] : 0.f;
  float vals[4];
  #pragma unroll
  for(int d=0;d<3;++d)
    vals[d] = (tid<Nn)? (xf[(b*Nn+tid)*3+d]-x0[(b*Nn+tid)*3+d])*nmv : 0.f;
  vals[3]=nmv;
  #pragma unroll
  for(int q=0;q<4;++q){
    sh[tid]=vals[q]; __syncthreads();
    for(int s=64;s>0;s>>=1){ if(tid<s) sh[tid]+=sh[tid+s]; __syncthreads(); }
    if(tid==0) vstat[b*4+q]=sh[0];
    __syncthreads();
  }
}

// ---------------- output
__global__ void k_out(const float* h, const float* xf, const float* x0, fp nm,
                      const float* vstat, fp W_out, fp b_out, float* out){
  __shared__ float shh[HD];
  int bn=blockIdx.x, tid=threadIdx.x, b=bn/Nn;
  shh[tid]=h[bn*HD+tid]; __syncthreads();
  float nmv=nm[bn];
  if(tid<3){
    float vel=(xf[bn*3+tid]-x0[bn*3+tid])*nmv;
    float mean=vstat[b*4+tid]/vstat[b*4+3];
    out[bn*(NDIM+HFEAT)+tid]=vel-mean*nmv;
  } else if(tid<3+HFEAT){
    int f=tid-3;
    float acc=b_out[f];
    for(int k=0;k<HD;++k) acc+=shh[k]*W_out[k*FINC+f];
    out[bn*(NDIM+HFEAT)+tid]=acc*nmv;
  }
}

extern "C" void kernel_launch(void* const* d_in, const int* in_sizes, int n_in,
                              void* d_out, int out_size, void* d_ws, size_t ws_size,
                              hipStream_t stream) {
  fp xh   =(fp)d_in[0];
  fp t    =(fp)d_in[1];
  fp nm   =(fp)d_in[2];
  // d_in[3] edge_mask: reproduced exactly as nm_i*nm_j*(i!=j), not read
  fp W_emb=(fp)d_in[4],  b_emb=(fp)d_in[5];
  fp gWe1 =(fp)d_in[6],  gbe1 =(fp)d_in[7];
  fp gWe2 =(fp)d_in[8],  gbe2 =(fp)d_in[9];
  fp gWn1 =(fp)d_in[10], gbn1 =(fp)d_in[11];
  fp gWn2 =(fp)d_in[12], gbn2 =(fp)d_in[13];
  fp eWc1 =(fp)d_in[14], ebc1 =(fp)d_in[15];
  fp eWc2 =(fp)d_in[16], ebc2 =(fp)d_in[17];
  fp eWc3 =(fp)d_in[18];
  fp W_out=(fp)d_in[19], b_out=(fp)d_in[20];

  // ws layout: bf16 B-frag bank first (16B aligned), then fp32 scratch
  unsigned short* w2b = (unsigned short*)d_ws;          // 12*16384 ushorts = 384 KB
  float* fbase = (float*)((char*)d_ws + 12*HD*HD*sizeof(unsigned short));
  float* h    = fbase;            // BN*HD
  float* Hi   = h   + BN*HD;
  float* Hj   = Hi  + BN*HD;
  float* agg  = Hj  + BN*HD;
  float* x0   = agg + BN*HD;      // BN*3
  float* xA   = x0  + BN*3;
  float* xB   = xA  + BN*3;
  float* vstat= xB  + BN*3;       // BSZ*4

  k_prep <<<12,256,0,stream>>>(gWe2, eWc2, w2b);
  k_embed<<<BN,128,0,stream>>>(xh,t,nm,W_emb,b_emb,h,x0,xA);
  float* xc=xA; float* xn=xB;
  for(int l=0;l<4;++l){
    for(int s=0;s<2;++s){
      int g=l*2+s;
      k_hij <<<BN/4,512,0,stream>>>(h, gWe1+(size_t)g*258*HD, gbe1+(size_t)g*HD, Hi, Hj);
      k_pair<<<BN,512,0,stream>>>(Hi,Hj,xc,x0,nm,
            gWe1+(size_t)g*258*HD, w2b+(size_t)g*HD*HD, gbe2+(size_t)g*HD, agg);
      k_node<<<BN/4,512,0,stream>>>(h,agg,
            gWn1+(size_t)g*256*HD, gbn1+(size_t)g*HD,
            gWn2+(size_t)g*HD*HD, gbn2+(size_t)g*HD, nm);
    }
    k_hij  <<<BN/4,512,0,stream>>>(h, eWc1+(size_t)l*258*HD, ebc1+(size_t)l*HD, Hi, Hj);
    k_coord<<<BN,512,0,stream>>>(Hi,Hj,xc,x0,nm,
            eWc1+(size_t)l*258*HD, w2b+(size_t)(8+l)*HD*HD, ebc2+(size_t)l*HD,
            eWc3+(size_t)l*HD, xn);
    float* tmp=xc; xc=xn; xn=tmp;
  }
  k_velstat<<<BSZ,128,0,stream>>>(xc,x0,nm,vstat);
  k_out   <<<BN,128,0,stream>>>(h,xc,x0,nm,vstat,W_out,b_out,(float*)d_out);
}